// Round 1
// baseline (835.712 us; speedup 1.0000x reference)
//
#include <hip/hip_runtime.h>
#include <cmath>

// Problem constants (N=2, S=512, C=512, H=W=50, OUT=7, RATIO=2)
#define NIMG 2
#define SPROP 512
#define NROI 1024          // NIMG*SPROP
#define CCH 512
#define FH 50
#define FW 50
#define K1 25088           // CCH*7*7
#define HID 1024
#define NCLS 21
#define NDET 100
#define IMGSZ 800.0f
#define LOGMAX 4.135166556742356f   // log(1000/16)
#define MCAND 10240        // SPROP*(NCLS-1)
#define ZSPLIT 8
#define KCHUNK 3136        // K1/ZSPLIT
#define ZSPLIT2 4
#define KCHUNK2 256        // HID/ZSPLIT2

typedef unsigned short u16;
typedef __attribute__((ext_vector_type(8))) short short8;
typedef __attribute__((ext_vector_type(4))) float f32x4;
typedef __attribute__((ext_vector_type(16))) float f32x16;

__device__ __forceinline__ u16 f2bf(float x) {        // RTNE fp32 -> bf16
  unsigned int u = __float_as_uint(x);
  u += 0x7fffu + ((u >> 16) & 1u);
  return (u16)(u >> 16);
}
__device__ __forceinline__ float bf2f(u16 h) {
  return __uint_as_float(((unsigned int)h) << 16);
}

// ------------------------------------------------------------ ROI align
template <bool BF16OUT>
__global__ __launch_bounds__(256) void roi_kernel(
    const float* __restrict__ feat, const float* __restrict__ props,
    float* __restrict__ X, u16* __restrict__ Xhi, u16* __restrict__ Xlo) {
  const int r = blockIdx.x;
  const int n = r >> 9;
  const int tid = threadIdx.x;
  __shared__ float tile[32][256];   // 32 ch x (16x16 px) = 32 KB
  __shared__ int sy0[14], sy1[14], sx0[14], sx1[14];
  __shared__ float sly[14], slx[14], svy[14], svx[14];

  const float p0 = props[r * 4 + 0] * 0.0625f;
  const float p1 = props[r * 4 + 1] * 0.0625f;
  const float p2 = props[r * 4 + 2] * 0.0625f;
  const float p3 = props[r * 4 + 3] * 0.0625f;
  const float bw = fmaxf(p2 - p0, 1.0f) / 7.0f;
  const float bh = fmaxf(p3 - p1, 1.0f) / 7.0f;

  if (tid < 14) {
    const int j = tid;
    const float g = (float)(j >> 1) + ((float)(j & 1) + 0.5f) * 0.5f;
    float y = p1 + g * bh;
    svy[j] = (y > -1.0f && y < (float)FH) ? 1.0f : 0.0f;
    float yc = fminf(fmaxf(y, 0.0f), (float)(FH - 1));
    int y0 = (int)floorf(yc);
    sy0[j] = y0; sy1[j] = min(y0 + 1, FH - 1); sly[j] = yc - (float)y0;
    float x = p0 + g * bw;
    svx[j] = (x > -1.0f && x < (float)FW) ? 1.0f : 0.0f;
    float xc = fminf(fmaxf(x, 0.0f), (float)(FW - 1));
    int x0 = (int)floorf(xc);
    sx0[j] = x0; sx1[j] = min(x0 + 1, FW - 1); slx[j] = xc - (float)x0;
  }
  __syncthreads();
  const int ymin = sy0[0], xmin = sx0[0];
  const float* fb = feat + (size_t)n * CCH * (FH * FW);

  for (int cc = 0; cc < 16; ++cc) {
    const int c0 = cc * 32;
#pragma unroll
    for (int e = 0; e < 32; ++e) {
      const int idx = tid + e * 256;
      const int c = idx >> 8, p = idx & 255;
      const int gy = min(ymin + (p >> 4), FH - 1);
      const int gx = min(xmin + (p & 15), FW - 1);
      tile[c][p] = fb[(size_t)(c0 + c) * (FH * FW) + gy * FW + gx];
    }
    __syncthreads();
#pragma unroll
    for (int e = 0; e < 7; ++e) {
      const int idx = tid + e * 256;
      if (idx < 1568) {
        const int c = idx / 49;
        const int s = idx - c * 49;
        const int oy = s / 7, ox = s - (s / 7) * 7;
        float acc = 0.0f;
#pragma unroll
        for (int sy = 0; sy < 2; ++sy) {
          const int yj = oy * 2 + sy;
          const int py0 = sy0[yj] - ymin, py1 = sy1[yj] - ymin;
          const float ly = sly[yj], vy = svy[yj];
#pragma unroll
          for (int sx = 0; sx < 2; ++sx) {
            const int xj = ox * 2 + sx;
            const int px0 = sx0[xj] - xmin, px1 = sx1[xj] - xmin;
            const float lx = slx[xj], vx = svx[xj];
            const float f00 = tile[c][py0 * 16 + px0];
            const float f01 = tile[c][py0 * 16 + px1];
            const float f10 = tile[c][py1 * 16 + px0];
            const float f11 = tile[c][py1 * 16 + px1];
            float v = f00 * (1.0f - ly) * (1.0f - lx) + f01 * (1.0f - ly) * lx +
                      f10 * ly * (1.0f - lx) + f11 * ly * lx;
            acc += v * (vy * vx);
          }
        }
        const float v = acc * 0.25f;
        const size_t k = (size_t)r * K1 + (size_t)(c0 + c) * 49 + s;
        if (BF16OUT) {
          const u16 h = f2bf(v);
          Xhi[k] = h;
          Xlo[k] = f2bf(v - bf2f(h));
        } else {
          X[k] = v;
        }
      }
    }
    __syncthreads();
  }
}

// ------------------------- w -> hi/lo bf16, transposed to [n][k]
// Generic over K dimension (w1: K1 x HID, w2: HID x HID), both [k][n] in.
template <int KDIM>
__global__ __launch_bounds__(256) void convw_kernel(
    const float* __restrict__ w, u16* __restrict__ Wh, u16* __restrict__ Wl) {
  __shared__ u16 sh[64][65], sl[64][65];
  const int k0 = blockIdx.x * 64;
  const int n0 = blockIdx.y * 64;
  const int t = threadIdx.x;
#pragma unroll
  for (int e = 0; e < 16; ++e) {
    const int idx = t + e * 256;
    const int kl = idx >> 6, nl = idx & 63;
    const float v = w[(size_t)(k0 + kl) * HID + n0 + nl];
    const u16 h = f2bf(v);
    sh[kl][nl] = h;
    sl[kl][nl] = f2bf(v - bf2f(h));
  }
  __syncthreads();
#pragma unroll
  for (int e = 0; e < 16; ++e) {
    const int idx = t + e * 256;
    const int nl = idx >> 6, kl = idx & 63;
    Wh[(size_t)(n0 + nl) * KDIM + k0 + kl] = sh[kl][nl];
    Wl[(size_t)(n0 + nl) * KDIM + k0 + kl] = sl[kl][nl];
  }
}

// --------------- split-bf16 MFMA GEMM (32x32x16), generic K-stride / K-chunk
// Used for FC1 (KS=K1, KCH=3136, z=8) and FC2 (KS=HID, KCH=256, z=4).
// Round-8 change: T14 async-STAGE split. Old loop was fully serial
// (load -> ds_write -> bar -> compute -> bar): the vmcnt(0) before the
// ds_writes sat right after load issue, exposing full L2/HBM latency every
// K-step (MfmaUtil ~32%). Now K-step t+1's loads are issued right after
// barrier #1, so their vmcnt drain lands at the NEXT iteration's ds_writes —
// hidden under the ~24-MFMA compute phase. Layout/numerics unchanged.
// A/B frag: [row = lane&31][k = (lane>>5)*8 + j].
// C/D: col = lane&31, row = (reg&3) + 8*(reg>>2) + 4*(lane>>5)  [m74/m101].
template <int KS, int KCH>
__global__ __launch_bounds__(256, 2) void gemm_mfma_split(
    const u16* __restrict__ Ahg, const u16* __restrict__ Alg,
    const u16* __restrict__ Bhg, const u16* __restrict__ Blg,
    float* __restrict__ CP) {
  __shared__ u16 Ah[128][40], Al[128][40], Bh[128][40], Bl[128][40];
  const int tid = threadIdx.x;
  const int lane = tid & 63;
  const int wv = tid >> 6;
  const int wm = (wv >> 1) * 64;
  const int wn = (wv & 1) * 64;
  const int mT = blockIdx.y << 7;
  const int nT = blockIdx.x << 7;
  const int kz = blockIdx.z * KCH;

  const int r0 = tid >> 2, q0 = (tid & 3) << 3;
  const int r1 = r0 + 64;

  f32x16 acc[2][2];
#pragma unroll
  for (int i = 0; i < 2; ++i)
#pragma unroll
    for (int j = 0; j < 2; ++j)
#pragma unroll
      for (int e = 0; e < 16; ++e) acc[i][j][e] = 0.0f;

  const size_t a0off = (size_t)(mT + r0) * KS + q0;
  const size_t a1off = (size_t)(mT + r1) * KS + q0;
  const size_t b0off = (size_t)(nT + r0) * KS + q0;
  const size_t b1off = (size_t)(nT + r1) * KS + q0;

  const int fm = lane & 31;          // row within 32-tile
  const int fq = (lane >> 5) << 3;   // k-subgroup offset (0 or 8)

  // prologue: stage K-step 0 into registers
  uint4 va0 = *(const uint4*)(Ahg + a0off + kz);
  uint4 va1 = *(const uint4*)(Ahg + a1off + kz);
  uint4 vl0 = *(const uint4*)(Alg + a0off + kz);
  uint4 vl1 = *(const uint4*)(Alg + a1off + kz);
  uint4 vb0 = *(const uint4*)(Bhg + b0off + kz);
  uint4 vb1 = *(const uint4*)(Bhg + b1off + kz);
  uint4 vm0 = *(const uint4*)(Blg + b0off + kz);
  uint4 vm1 = *(const uint4*)(Blg + b1off + kz);

  for (int kb = kz; kb < kz + KCH; kb += 32) {
    // write staged regs to LDS (vmcnt wait lands here, after prev compute)
    *(uint4*)(&Ah[r0][q0]) = va0;
    *(uint4*)(&Ah[r1][q0]) = va1;
    *(uint4*)(&Al[r0][q0]) = vl0;
    *(uint4*)(&Al[r1][q0]) = vl1;
    *(uint4*)(&Bh[r0][q0]) = vb0;
    *(uint4*)(&Bh[r1][q0]) = vb1;
    *(uint4*)(&Bl[r0][q0]) = vm0;
    *(uint4*)(&Bl[r1][q0]) = vm1;
    __syncthreads();

    // issue next K-step's loads now: latency hides under the MFMA phase
    const int kn = kb + 32;
    if (kn < kz + KCH) {
      va0 = *(const uint4*)(Ahg + a0off + kn);
      va1 = *(const uint4*)(Ahg + a1off + kn);
      vl0 = *(const uint4*)(Alg + a0off + kn);
      vl1 = *(const uint4*)(Alg + a1off + kn);
      vb0 = *(const uint4*)(Bhg + b0off + kn);
      vb1 = *(const uint4*)(Bhg + b1off + kn);
      vm0 = *(const uint4*)(Blg + b0off + kn);
      vm1 = *(const uint4*)(Blg + b1off + kn);
    }

#pragma unroll
    for (int kh = 0; kh < 2; ++kh) {
      const int ko = kh * 16 + fq;
      short8 fah[2], fal[2], fbh[2], fbl[2];
#pragma unroll
      for (int t = 0; t < 2; ++t) {
        fah[t] = *(const short8*)(&Ah[wm + t * 32 + fm][ko]);
        fal[t] = *(const short8*)(&Al[wm + t * 32 + fm][ko]);
        fbh[t] = *(const short8*)(&Bh[wn + t * 32 + fm][ko]);
        fbl[t] = *(const short8*)(&Bl[wn + t * 32 + fm][ko]);
      }
#pragma unroll
      for (int ti = 0; ti < 2; ++ti)
#pragma unroll
        for (int tj = 0; tj < 2; ++tj) {
          acc[ti][tj] = __builtin_amdgcn_mfma_f32_32x32x16_bf16(
              fah[ti], fbh[tj], acc[ti][tj], 0, 0, 0);
          acc[ti][tj] = __builtin_amdgcn_mfma_f32_32x32x16_bf16(
              fah[ti], fbl[tj], acc[ti][tj], 0, 0, 0);
          acc[ti][tj] = __builtin_amdgcn_mfma_f32_32x32x16_bf16(
              fal[ti], fbh[tj], acc[ti][tj], 0, 0, 0);
        }
    }
    __syncthreads();
  }

  float* Cp = CP + (size_t)blockIdx.z * ((size_t)NROI * HID);
  const int ccol = nT + wn + (lane & 31);
  const int rbase = mT + wm + 4 * (lane >> 5);
#pragma unroll
  for (int ti = 0; ti < 2; ++ti)
#pragma unroll
    for (int tj = 0; tj < 2; ++tj)
#pragma unroll
      for (int rg = 0; rg < 16; ++rg) {
        const int row = rbase + ti * 32 + (rg & 3) + 8 * (rg >> 2);
        Cp[(size_t)row * HID + ccol + tj * 32] = acc[ti][tj][rg];
      }
}

// ------------------------------------------------------- FC1 fallback (fp32)
__global__ __launch_bounds__(256) void gemm1_kernel(
    const float* __restrict__ A, const float* __restrict__ B,
    float* __restrict__ CP) {
  __shared__ float As[16][68];
  __shared__ float Bs[16][68];
  const int tid = threadIdx.x;
  const int mTile = blockIdx.y << 6;
  const int nTile = blockIdx.x << 6;
  const int k0 = blockIdx.z * KCHUNK;
  const int ty = tid >> 4, tx = tid & 15;
  const int ar = tid >> 2, ac = (tid & 3) << 2;
  const int br = tid >> 4, bcl = (tid & 15) << 2;
  float acc[4][4] = {};

  for (int kb = k0; kb < k0 + KCHUNK; kb += 16) {
    const float4 av = *(const float4*)(A + (size_t)(mTile + ar) * K1 + kb + ac);
    const float4 bv = *(const float4*)(B + (size_t)(kb + br) * HID + nTile + bcl);
    As[ac + 0][ar] = av.x; As[ac + 1][ar] = av.y;
    As[ac + 2][ar] = av.z; As[ac + 3][ar] = av.w;
    *(float4*)(&Bs[br][bcl]) = bv;
    __syncthreads();
#pragma unroll
    for (int kk = 0; kk < 16; ++kk) {
      const float4 a4 = *(const float4*)(&As[kk][ty << 2]);
      const float4 b4 = *(const float4*)(&Bs[kk][tx << 2]);
      const float aa[4] = {a4.x, a4.y, a4.z, a4.w};
      const float bb4[4] = {b4.x, b4.y, b4.z, b4.w};
#pragma unroll
      for (int i = 0; i < 4; ++i)
#pragma unroll
        for (int j = 0; j < 4; ++j)
          acc[i][j] = fmaf(aa[i], bb4[j], acc[i][j]);
    }
    __syncthreads();
  }
  float* Cp = CP + (size_t)blockIdx.z * (HID * NROI);
#pragma unroll
  for (int i = 0; i < 4; ++i) {
    *(float4*)(Cp + (size_t)(mTile + (ty << 2) + i) * HID + nTile + (tx << 2)) =
        make_float4(acc[i][0], acc[i][1], acc[i][2], acc[i][3]);
  }
}

// reduce 8 K-partials + bias + relu -> H1 as split-bf16 (feeds FC2 MFMA)
__global__ __launch_bounds__(256) void bias_relu_bf16_kernel(
    const float* __restrict__ CP, const float* __restrict__ b1,
    u16* __restrict__ H1h, u16* __restrict__ H1l) {
  const int idx = blockIdx.x * 256 + threadIdx.x;
  float v = b1[idx & (HID - 1)];
#pragma unroll
  for (int z = 0; z < ZSPLIT; ++z) v += CP[(size_t)z * (HID * NROI) + idx];
  v = fmaxf(v, 0.0f);
  const u16 h = f2bf(v);
  H1h[idx] = h;
  H1l[idx] = f2bf(v - bf2f(h));
}

// fp32 variant for the fallback path
__global__ __launch_bounds__(256) void bias_relu_f32_kernel(
    const float* __restrict__ CP, const float* __restrict__ b1,
    float* __restrict__ H1) {
  const int idx = blockIdx.x * 256 + threadIdx.x;
  float v = b1[idx & (HID - 1)];
#pragma unroll
  for (int z = 0; z < ZSPLIT; ++z) v += CP[(size_t)z * (HID * NROI) + idx];
  H1[idx] = fmaxf(v, 0.0f);
}

// reduce 4 K-partials of FC2 + bias + relu -> H2 fp32
__global__ __launch_bounds__(256) void bias_relu2_kernel(
    const float* __restrict__ CP2, const float* __restrict__ b2,
    float* __restrict__ H2) {
  const int idx = blockIdx.x * 256 + threadIdx.x;
  float v = b2[idx & (HID - 1)];
#pragma unroll
  for (int z = 0; z < ZSPLIT2; ++z) v += CP2[(size_t)z * (HID * NROI) + idx];
  H2[idx] = fmaxf(v, 0.0f);
}

// ------------------------------------------------------------- FC2 (K=1024)
// fp32 fallback only (bf16 path uses gemm_mfma_split<HID, KCHUNK2>)
__global__ __launch_bounds__(256) void gemm2_kernel(
    const float* __restrict__ A, const float* __restrict__ B,
    const float* __restrict__ bias, float* __restrict__ C) {
  __shared__ float As[16][68];
  __shared__ float Bs[16][68];
  const int tid = threadIdx.x;
  const int mTile = blockIdx.y << 6;
  const int nTile = blockIdx.x << 6;
  const int ty = tid >> 4, tx = tid & 15;
  const int ar = tid >> 2, ac = (tid & 3) << 2;
  const int br = tid >> 4, bcl = (tid & 15) << 2;
  float acc[4][4] = {};

  for (int kb = 0; kb < HID; kb += 16) {
    const float4 av = *(const float4*)(A + (size_t)(mTile + ar) * HID + kb + ac);
    const float4 bv = *(const float4*)(B + (size_t)(kb + br) * HID + nTile + bcl);
    As[ac + 0][ar] = av.x; As[ac + 1][ar] = av.y;
    As[ac + 2][ar] = av.z; As[ac + 3][ar] = av.w;
    *(float4*)(&Bs[br][bcl]) = bv;
    __syncthreads();
#pragma unroll
    for (int kk = 0; kk < 16; ++kk) {
      const float4 a4 = *(const float4*)(&As[kk][ty << 2]);
      const float4 b4 = *(const float4*)(&Bs[kk][tx << 2]);
      const float aa[4] = {a4.x, a4.y, a4.z, a4.w};
      const float bb4[4] = {b4.x, b4.y, b4.z, b4.w};
#pragma unroll
      for (int i = 0; i < 4; ++i)
#pragma unroll
        for (int j = 0; j < 4; ++j)
          acc[i][j] = fmaf(aa[i], bb4[j], acc[i][j]);
    }
    __syncthreads();
  }
#pragma unroll
  for (int i = 0; i < 4; ++i) {
#pragma unroll
    for (int j = 0; j < 4; ++j) {
      float v = acc[i][j] + bias[nTile + (tx << 2) + j];
      acc[i][j] = fmaxf(v, 0.0f);
    }
    *(float4*)(C + (size_t)(mTile + (ty << 2) + i) * HID + nTile + (tx << 2)) =
        make_float4(acc[i][0], acc[i][1], acc[i][2], acc[i][3]);
  }
}

// ------------------- heads: cls+box dots, softmax, decode, candidate arrays
// Candidate layout is CLASS-MAJOR: index = n*MCAND + (k-1)*SPROP + s
__global__ __launch_bounds__(128) void heads_kernel(
    const float* __restrict__ H2m, const float* __restrict__ wc,
    const float* __restrict__ bc, const float* __restrict__ wb,
    const float* __restrict__ bb, const float* __restrict__ props,
    float* __restrict__ BX2, float* __restrict__ NB2,
    float* __restrict__ LV2) {
  const int r = blockIdx.x;
  const int tid = threadIdx.x;
  __shared__ float hrow[HID];
  __shared__ float vals[112];
  __shared__ float red[2];

  for (int i = tid; i < HID; i += 128) hrow[i] = H2m[(size_t)r * HID + i];
  __syncthreads();

  if (tid < 105) {
    float acc;
    if (tid < NCLS) {
      acc = bc[tid];
      for (int kk = 0; kk < HID; ++kk) acc = fmaf(hrow[kk], wc[kk * NCLS + tid], acc);
    } else {
      const int j = tid - NCLS;
      acc = bb[j];
      for (int kk = 0; kk < HID; ++kk) acc = fmaf(hrow[kk], wb[kk * (NCLS * 4) + j], acc);
    }
    vals[tid] = acc;
  }
  __syncthreads();

  if (tid == 0) {
    float m = vals[0];
    for (int k = 1; k < NCLS; ++k) m = fmaxf(m, vals[k]);
    float s = 0.0f;
    for (int k = 0; k < NCLS; ++k) s += expf(vals[k] - m);
    red[0] = m;
    red[1] = 1.0f / s;
  }
  __syncthreads();

  if (tid >= 1 && tid <= 20) {
    const int k = tid;
    const float prob = expf(vals[k] - red[0]) * red[1];

    const float px1 = props[r * 4 + 0], py1 = props[r * 4 + 1];
    const float px2 = props[r * 4 + 2], py2 = props[r * 4 + 3];
    const float pw = px2 - px1, ph = py2 - py1;
    const float pcx = px1 + 0.5f * pw, pcy = py1 + 0.5f * ph;

    const float dx = vals[NCLS + k * 4 + 0] / 10.0f;
    const float dy = vals[NCLS + k * 4 + 1] / 10.0f;
    const float dw = fminf(vals[NCLS + k * 4 + 2] / 5.0f, LOGMAX);
    const float dh = fminf(vals[NCLS + k * 4 + 3] / 5.0f, LOGMAX);

    const float cx = dx * pw + pcx, cy = dy * ph + pcy;
    const float w = expf(dw) * pw, h = expf(dh) * ph;
    float b0 = cx - 0.5f * w, b1c = cy - 0.5f * h;
    float b2 = cx + 0.5f * w, b3 = cy + 0.5f * h;
    b0 = fminf(fmaxf(b0, 0.0f), IMGSZ);
    b1c = fminf(fmaxf(b1c, 0.0f), IMGSZ);
    b2 = fminf(fmaxf(b2, 0.0f), IMGSZ);
    b3 = fminf(fmaxf(b3, 0.0f), IMGSZ);

    const float wv = b2 - b0, hv = b3 - b1c;
    const bool valid = (prob > 0.05f) && (wv >= 0.01f) && (hv >= 0.01f);

    const int n = r >> 9, s = r & 511;
    const int cand = (k - 1) * SPROP + s;     // class-major
    const size_t bi = (size_t)n * MCAND + cand;
    const float off = (float)k * (IMGSZ + 1.0f);

    BX2[bi * 4 + 0] = b0; BX2[bi * 4 + 1] = b1c;
    BX2[bi * 4 + 2] = b2; BX2[bi * 4 + 3] = b3;
    NB2[bi * 4 + 0] = b0 + off; NB2[bi * 4 + 1] = b1c + off;
    NB2[bi * 4 + 2] = b2 + off; NB2[bi * 4 + 3] = b3 + off;
    LV2[bi] = valid ? prob : -1.0f;
  }
}

// ---------------------------------------------- per-(image,class) greedy NMS
// Cross-class IoU == 0 (801*k offsets), so the global greedy restricted to a
// class equals the standalone per-class greedy (proved by induction on picks).
// One wave per (n,c): 512 slots in registers, barrier-free serial loop.
template <int CTRL>
__device__ __forceinline__ void red2(float& v, int& ix) {
  const float tv = __int_as_float(__builtin_amdgcn_update_dpp(
      (int)0xC0000000, __float_as_int(v), CTRL, 0xf, 0xf, false));
  const int ti = __builtin_amdgcn_update_dpp(0x7fffffff, ix, CTRL, 0xf, 0xf, false);
  if (tv > v || (tv == v && ti < ix)) { v = tv; ix = ti; }
}
__device__ __forceinline__ void wave_red2(float& v, int& ix) {
  red2<0x111>(v, ix);  // row_shr:1
  red2<0x112>(v, ix);  // row_shr:2
  red2<0x114>(v, ix);  // row_shr:4
  red2<0x118>(v, ix);  // row_shr:8
  red2<0x142>(v, ix);  // row_bcast:15
  red2<0x143>(v, ix);  // row_bcast:31 -> lane 63 holds winner
}

__global__ __launch_bounds__(64) void nms_class_kernel(
    const float* __restrict__ NB2, const float* __restrict__ LV2,
    float* __restrict__ ksg, int* __restrict__ kig, int* __restrict__ cntg) {
  const int bid = blockIdx.x;           // n*20 + c
  const int lane = threadIdx.x;         // 0..63
  __shared__ float4 lbox[SPROP];        // winner-broadcast copy
  const size_t cb = (size_t)bid * SPROP;

  float lv[8], b0[8], b1[8], b2[8], b3[8], ar[8];
#pragma unroll
  for (int j = 0; j < 8; ++j) {
    const int s = lane + j * 64;
    lv[j] = LV2[cb + s];
    const float4 b = *(const float4*)(NB2 + (cb + s) * 4);
    b0[j] = b.x; b1[j] = b.y; b2[j] = b.z; b3[j] = b.w;
    ar[j] = (b.z - b.x) * (b.w - b.y);
    lbox[s] = b;
  }

  int cnt = 0;
  for (int d = 0; d < NDET; ++d) {
    float bv = -2.0f;
    int bix = 0x7fffffff;
#pragma unroll
    for (int j = 0; j < 8; ++j) {     // j asc => slot asc; strict > keeps lowest
      if (lv[j] > bv) { bv = lv[j]; bix = lane + j * 64; }
    }
    wave_red2(bv, bix);
    const float bv2 = __shfl(bv, 63);
    const int bix2 = __shfl(bix, 63);
    if (bv2 <= 0.05f) break;          // all remaining dead; wave-uniform

    if (lane == 0) {
      ksg[bid * NDET + cnt] = bv2;
      kig[bid * NDET + cnt] = bix2;   // slot within class (0..511)
    }
    ++cnt;

    const float4 wb = lbox[bix2];     // same-wave LDS write->read, waitcnt ok
    const float wa = (wb.z - wb.x) * (wb.w - wb.y);
#pragma unroll
    for (int j = 0; j < 8; ++j) {
      const float xx1 = fmaxf(wb.x, b0[j]);
      const float yy1 = fmaxf(wb.y, b1[j]);
      const float xx2 = fminf(wb.z, b2[j]);
      const float yy2 = fminf(wb.w, b3[j]);
      const float inter = fmaxf(xx2 - xx1, 0.0f) * fmaxf(yy2 - yy1, 0.0f);
      const float iou = inter / (wa + ar[j] - inter + 1e-9f);
      if (iou > 0.5f) lv[j] = -1.0f;
    }
  }
  if (lane == 0) cntg[bid] = cnt;
}

// ------------------------------- merge: top-100 by (score desc, flat-idx asc)
// Global greedy order == keeps sorted by packed priority (scores non-increasing
// along greedy; tied keeps are simultaneously live so argmax first-index rule
// = lowest flat idx). Rank-based selection: zero barriers in the hot loop.
__global__ __launch_bounds__(1024) void nms_merge_kernel(
    const float* __restrict__ ksg, const int* __restrict__ kig,
    const int* __restrict__ cntg, const float* __restrict__ BX2,
    float* __restrict__ out) {
  const int n = blockIdx.x;
  const int tid = threadIdx.x;
  __shared__ int cbase[21];
  __shared__ unsigned long long keys[2000];
  __shared__ float ssc[2000];
  __shared__ int sfl[2000];
  __shared__ float svals[NDET];
  __shared__ int sflat[NDET];

  if (tid == 0) {
    int acc = 0;
    for (int c = 0; c < 20; ++c) { cbase[c] = acc; acc += cntg[n * 20 + c]; }
    cbase[20] = acc;
  }
  __syncthreads();
  const int T = cbase[20];     // <= 2000

  for (int idx = tid; idx < 20 * NDET; idx += 1024) {
    const int c = idx / NDET, e = idx - (idx / NDET) * NDET;
    if (e < cntg[n * 20 + c]) {
      const int pos = cbase[c] + e;
      const float s = ksg[(n * 20 + c) * NDET + e];
      const int slot = kig[(n * 20 + c) * NDET + e];
      const int flat = slot * 20 + c;            // original flat candidate idx
      ssc[pos] = s;
      sfl[pos] = flat;
      keys[pos] = ((unsigned long long)__float_as_uint(s) << 32) |
                  (unsigned long long)(0xFFFFFFFFu - (unsigned)flat);
    }
  }
  __syncthreads();

  float msc[2]; int mfl[2]; unsigned long long mk[2]; int rank[2] = {0, 0};
  bool own[2];
#pragma unroll
  for (int e = 0; e < 2; ++e) {
    const int i = tid + e * 1024;
    own[e] = (i < T);
    if (own[e]) { mk[e] = keys[i]; msc[e] = ssc[i]; mfl[e] = sfl[i]; }
  }
  for (int i = 0; i < T; ++i) {        // LDS broadcast read per iteration
    const unsigned long long k = keys[i];
    if (own[0] && k > mk[0]) ++rank[0];
    if (own[1] && k > mk[1]) ++rank[1];
  }
#pragma unroll
  for (int e = 0; e < 2; ++e)
    if (own[e] && rank[e] < NDET) { svals[rank[e]] = msc[e]; sflat[rank[e]] = mfl[e]; }
  __syncthreads();

  if (tid < NDET) {
    const int m = (T < NDET) ? T : NDET;
    const bool keep = tid < m;
    float sv = 0.0f;
    float4 bx4 = make_float4(0.0f, 0.0f, 0.0f, 0.0f);
    float label = 0.0f;
    if (keep) {
      sv = svals[tid];
      const int flat = sflat[tid];
      const int c = flat % 20, s = flat / 20;
      bx4 = *(const float4*)(BX2 + ((size_t)(n * 20 + c) * SPROP + s) * 4);
      label = (float)(c + 1);
    }
    out[(n * NDET + tid) * 4 + 0] = bx4.x;
    out[(n * NDET + tid) * 4 + 1] = bx4.y;
    out[(n * NDET + tid) * 4 + 2] = bx4.z;
    out[(n * NDET + tid) * 4 + 3] = bx4.w;
    out[NIMG * NDET * 4 + n * NDET + tid] = sv;
    out[NIMG * NDET * 4 + NIMG * NDET + n * NDET + tid] = label;
  }
}

// ---------------------------------------------------------------- launcher
extern "C" void kernel_launch(void* const* d_in, const int* in_sizes, int n_in,
                              void* d_out, int out_size, void* d_ws, size_t ws_size,
                              hipStream_t stream) {
  const float* features  = (const float*)d_in[0];
  const float* proposals = (const float*)d_in[1];
  const float* w1 = (const float*)d_in[2];
  const float* b1 = (const float*)d_in[3];
  const float* w2 = (const float*)d_in[4];
  const float* b2 = (const float*)d_in[5];
  const float* wc = (const float*)d_in[6];
  const float* bc = (const float*)d_in[7];
  const float* wb = (const float*)d_in[8];
  const float* bb = (const float*)d_in[9];

  const size_t XE = (size_t)NROI * K1;
  const size_t WE = (size_t)K1 * HID;
  const size_t FLOATS_TAIL =
      (size_t)ZSPLIT * NROI * HID + 2 * (size_t)NROI * HID + (size_t)NIMG * MCAND * 10;
  const size_t NEED = (XE * 2 + WE * 2) * sizeof(u16) + FLOATS_TAIL * sizeof(float);

  if (ws_size >= NEED) {
    u16* Xhi = (u16*)d_ws;
    u16* Xlo = Xhi + XE;
    u16* Wh  = Xlo + XE;
    u16* Wl  = Wh + WE;
    float* CP  = (float*)(Wl + WE);
    // CP region: 8 partials (33.5 MB); FC2's 4 partials (CP2) alias its head —
    // CP is dead after bias_relu_bf16, CP2 written only by the later FC2.
    float* CP2 = CP;
    float* H2  = CP + (size_t)ZSPLIT * NROI * HID;
    float* BX2 = H2 + (size_t)NROI * HID;
    float* NB2 = BX2 + (size_t)NIMG * MCAND * 4;
    float* LV2 = NB2 + (size_t)NIMG * MCAND * 4;
    float* ksg = LV2 + (size_t)NIMG * MCAND;
    int*   kig = (int*)(ksg + (size_t)NIMG * 20 * NDET);
    int*   cntg = kig + (size_t)NIMG * 20 * NDET;
    // H1 hi/lo alias the Xhi region (dead after FC1); W2t hi/lo alias Xlo.
    // Stream order guarantees safety: gemm1 reads X before these are written.
    u16* H1h = Xhi;
    u16* H1l = Xhi + (size_t)NROI * HID;
    u16* W2h = Xlo;
    u16* W2l = Xlo + (size_t)HID * HID;

    convw_kernel<K1><<<dim3(K1 / 64, HID / 64), 256, 0, stream>>>(w1, Wh, Wl);
    roi_kernel<true><<<NROI, 256, 0, stream>>>(features, proposals, nullptr, Xhi, Xlo);
    gemm_mfma_split<K1, KCHUNK><<<dim3(8, 8, ZSPLIT), 256, 0, stream>>>(
        Xhi, Xlo, Wh, Wl, CP);
    bias_relu_bf16_kernel<<<(NROI * HID) / 256, 256, 0, stream>>>(CP, b1, H1h, H1l);
    convw_kernel<HID><<<dim3(HID / 64, HID / 64), 256, 0, stream>>>(w2, W2h, W2l);
    gemm_mfma_split<HID, KCHUNK2><<<dim3(8, 8, ZSPLIT2), 256, 0, stream>>>(
        H1h, H1l, W2h, W2l, CP2);
    bias_relu2_kernel<<<(NROI * HID) / 256, 256, 0, stream>>>(CP2, b2, H2);
    heads_kernel<<<NROI, 128, 0, stream>>>(H2, wc, bc, wb, bb, proposals,
                                           BX2, NB2, LV2);
    nms_class_kernel<<<NIMG * 20, 64, 0, stream>>>(NB2, LV2, ksg, kig, cntg);
    nms_merge_kernel<<<NIMG, 1024, 0, stream>>>(ksg, kig, cntg, BX2,
                                                (float*)d_out);
  } else {
    float* ws = (float*)d_ws;
    float* X   = ws;
    float* CP  = X + XE;
    float* H1  = CP + (size_t)ZSPLIT * NROI * HID;
    float* H2  = H1 + (size_t)NROI * HID;
    float* BX2 = H2 + (size_t)NROI * HID;
    float* NB2 = BX2 + (size_t)NIMG * MCAND * 4;
    float* LV2 = NB2 + (size_t)NIMG * MCAND * 4;
    float* ksg = LV2 + (size_t)NIMG * MCAND;
    int*   kig = (int*)(ksg + (size_t)NIMG * 20 * NDET);
    int*   cntg = kig + (size_t)NIMG * 20 * NDET;

    roi_kernel<false><<<NROI, 256, 0, stream>>>(features, proposals, X, nullptr, nullptr);
    gemm1_kernel<<<dim3(16, 16, ZSPLIT), 256, 0, stream>>>(X, w1, CP);
    bias_relu_f32_kernel<<<(NROI * HID) / 256, 256, 0, stream>>>(CP, b1, H1);
    gemm2_kernel<<<dim3(16, 16), 256, 0, stream>>>(H1, w2, b2, H2);
    heads_kernel<<<NROI, 128, 0, stream>>>(H2, wc, bc, wb, bb, proposals,
                                           BX2, NB2, LV2);
    nms_class_kernel<<<NIMG * 20, 64, 0, stream>>>(NB2, LV2, ksg, kig, cntg);
    nms_merge_kernel<<<NIMG, 1024, 0, stream>>>(ksg, kig, cntg, BX2,
                                                (float*)d_out);
  }
}